// Round 1
// baseline (1989.858 us; speedup 1.0000x reference)
//
#include <hip/hip_runtime.h>
#include <hip/hip_bf16.h>
#include <math.h>

#define N_NODES 10000
#define E_EDGES 160000
#define EB 32    // edges per block
#define NB 16    // nodes per block (node kernel)

__device__ __forceinline__ float silu_f(float x) {
    return x / (1.0f + __expf(-x));
}

// ---------------------------------------------------------------------------
// Kernel A: X[n][0:256]   = h[n] @ eW1[0:512]      (Xr, for h[row] term)
//           X[n][256:512] = h[n] @ eW1[512:1024]   (Xc, for h[col] term)
//           X[n][512:768] = h[n] @ nW1[0:512]      (Y,  for node MLP)
// grid = (ceil(N/32), 3), block = 256 (thread j = output column)
// ---------------------------------------------------------------------------
__global__ __launch_bounds__(256) void precompute_X(
    const float* __restrict__ h, const float* __restrict__ eW1,
    const float* __restrict__ nW1, float* __restrict__ X)
{
    __shared__ float hs[32 * 64];
    const int n0 = blockIdx.x * 32;
    const int which = blockIdx.y;
    const float* W = (which == 2) ? nW1 : (eW1 + (size_t)which * 512 * 256);
    const int j = threadIdx.x;

    float acc[32];
#pragma unroll
    for (int r = 0; r < 32; ++r) acc[r] = 0.f;

    for (int kc = 0; kc < 512; kc += 64) {
#pragma unroll
        for (int i = 0; i < 8; ++i) {
            int li = j + i * 256;
            int r = li >> 6, c = li & 63;
            int n = n0 + r;
            hs[li] = (n < N_NODES) ? h[(size_t)n * 512 + kc + c] : 0.f;
        }
        __syncthreads();
#pragma unroll
        for (int k4 = 0; k4 < 16; ++k4) {
            float w0 = W[(size_t)(kc + k4 * 4 + 0) * 256 + j];
            float w1 = W[(size_t)(kc + k4 * 4 + 1) * 256 + j];
            float w2 = W[(size_t)(kc + k4 * 4 + 2) * 256 + j];
            float w3 = W[(size_t)(kc + k4 * 4 + 3) * 256 + j];
#pragma unroll
            for (int r = 0; r < 32; ++r) {
                const float4 hv = *reinterpret_cast<const float4*>(&hs[r * 64 + k4 * 4]);
                acc[r] = fmaf(hv.x, w0, fmaf(hv.y, w1, fmaf(hv.z, w2, fmaf(hv.w, w3, acc[r]))));
            }
        }
        __syncthreads();
    }
#pragma unroll
    for (int r = 0; r < 32; ++r) {
        int n = n0 + r;
        if (n < N_NODES) X[(size_t)n * 768 + which * 256 + j] = acc[r];
    }
}

// ---------------------------------------------------------------------------
// Kernel B: per-edge MLP + atomic aggregation.
// block = 256 threads (thread j = hidden column), EB=32 edges per block.
// ---------------------------------------------------------------------------
__global__ __launch_bounds__(256) void edge_kernel(
    const float* __restrict__ X, const float* __restrict__ pos,
    const int* __restrict__ eidx, const float* __restrict__ eattr,
    const float* __restrict__ eW1, const float* __restrict__ eb1,
    const float* __restrict__ eW2, const float* __restrict__ eb2,
    const float* __restrict__ cW1, const float* __restrict__ cb1,
    const float* __restrict__ cW2,
    float* __restrict__ agg_node, float* __restrict__ agg_coord)
{
    __shared__ float a_lds[EB * 256];   // 32 KB activation tile
    __shared__ float attr[EB * 52];     // padded stride 52 (16B-aligned rows)
    __shared__ int   ri[EB], ci[EB];
    __shared__ float dif[EB][3];
    __shared__ float rad[EB];
    __shared__ float uu[EB];
    __shared__ float red[EB * 4];

    const int e0 = blockIdx.x * EB;
    const int j = threadIdx.x;

    if (j < EB) {
        int e = e0 + j;
        int r = eidx[e];
        int c = eidx[E_EDGES + e];
        ri[j] = r; ci[j] = c;
        float dx = pos[r * 3 + 0] - pos[c * 3 + 0];
        float dy = pos[r * 3 + 1] - pos[c * 3 + 1];
        float dz = pos[r * 3 + 2] - pos[c * 3 + 2];
        dif[j][0] = dx; dif[j][1] = dy; dif[j][2] = dz;
        rad[j] = sqrtf(dx * dx + dy * dy + dz * dz) + 1e-8f;
    }
    // stage edge_attr: EB*51 contiguous floats
    for (int li = j; li < EB * 51; li += 256) {
        int e = li / 51, k = li - e * 51;
        attr[e * 52 + k] = eattr[(size_t)e0 * 51 + li];
    }
    __syncthreads();

    float acc[EB];

    // ---- stage 1: t1 = Xr[row] + Xc[col] + attr @ Wattr + radial*Wrad + eb1
    {
        float wrad = eW1[(size_t)1075 * 256 + j];
        float b1 = eb1[j];
#pragma unroll
        for (int e = 0; e < EB; ++e) {
            acc[e] = X[(size_t)ri[e] * 768 + j]
                   + X[(size_t)ci[e] * 768 + 256 + j]
                   + fmaf(rad[e], wrad, b1);
        }
        for (int k4 = 0; k4 < 12; ++k4) {
            float w0 = eW1[(size_t)(1024 + k4 * 4 + 0) * 256 + j];
            float w1 = eW1[(size_t)(1024 + k4 * 4 + 1) * 256 + j];
            float w2 = eW1[(size_t)(1024 + k4 * 4 + 2) * 256 + j];
            float w3 = eW1[(size_t)(1024 + k4 * 4 + 3) * 256 + j];
#pragma unroll
            for (int e = 0; e < EB; ++e) {
                const float4 a = *reinterpret_cast<const float4*>(&attr[e * 52 + k4 * 4]);
                acc[e] = fmaf(a.x, w0, fmaf(a.y, w1, fmaf(a.z, w2, fmaf(a.w, w3, acc[e]))));
            }
        }
        for (int k = 48; k < 51; ++k) {
            float w = eW1[(size_t)(1024 + k) * 256 + j];
#pragma unroll
            for (int e = 0; e < EB; ++e) acc[e] = fmaf(attr[e * 52 + k], w, acc[e]);
        }
    }
#pragma unroll
    for (int e = 0; e < EB; ++e) a_lds[e * 256 + j] = silu_f(acc[e]);
    __syncthreads();

    // ---- stage 2: e = silu(a1 @ eW2 + eb2)
    {
        float b2 = eb2[j];
#pragma unroll
        for (int e = 0; e < EB; ++e) acc[e] = b2;
        for (int k4 = 0; k4 < 64; ++k4) {
            float w0 = eW2[(size_t)(k4 * 4 + 0) * 256 + j];
            float w1 = eW2[(size_t)(k4 * 4 + 1) * 256 + j];
            float w2 = eW2[(size_t)(k4 * 4 + 2) * 256 + j];
            float w3 = eW2[(size_t)(k4 * 4 + 3) * 256 + j];
#pragma unroll
            for (int e = 0; e < EB; ++e) {
                const float4 a = *reinterpret_cast<const float4*>(&a_lds[e * 256 + k4 * 4]);
                acc[e] = fmaf(a.x, w0, fmaf(a.y, w1, fmaf(a.z, w2, fmaf(a.w, w3, acc[e]))));
            }
        }
    }
    __syncthreads();  // everyone done reading a_lds (stage-1 values)
#pragma unroll
    for (int e = 0; e < EB; ++e) {
        float v = silu_f(acc[e]);
        a_lds[e * 256 + j] = v;
        atomicAdd(&agg_node[(size_t)ri[e] * 256 + j], v);
    }
    __syncthreads();

    // ---- stage 3: c = silu(e @ cW1 + cb1); u = clip(c . cW2)
    {
        float b3 = cb1[j];
#pragma unroll
        for (int e = 0; e < EB; ++e) acc[e] = b3;
        for (int k4 = 0; k4 < 64; ++k4) {
            float w0 = cW1[(size_t)(k4 * 4 + 0) * 256 + j];
            float w1 = cW1[(size_t)(k4 * 4 + 1) * 256 + j];
            float w2 = cW1[(size_t)(k4 * 4 + 2) * 256 + j];
            float w3 = cW1[(size_t)(k4 * 4 + 3) * 256 + j];
#pragma unroll
            for (int e = 0; e < EB; ++e) {
                const float4 a = *reinterpret_cast<const float4*>(&a_lds[e * 256 + k4 * 4]);
                acc[e] = fmaf(a.x, w0, fmaf(a.y, w1, fmaf(a.z, w2, fmaf(a.w, w3, acc[e]))));
            }
        }
    }
    {
        float w2c = cW2[j];
        int lane = j & 63, wid = j >> 6;
#pragma unroll
        for (int e = 0; e < EB; ++e) {
            float v = silu_f(acc[e]) * w2c;
            v += __shfl_xor(v, 1);
            v += __shfl_xor(v, 2);
            v += __shfl_xor(v, 4);
            v += __shfl_xor(v, 8);
            v += __shfl_xor(v, 16);
            v += __shfl_xor(v, 32);
            if (lane == 0) red[e * 4 + wid] = v;
        }
    }
    __syncthreads();
    if (j < EB) {
        float u = red[j * 4 + 0] + red[j * 4 + 1] + red[j * 4 + 2] + red[j * 4 + 3];
        uu[j] = fminf(fmaxf(u, -1.f), 1.f);
    }
    __syncthreads();
    if (j < EB * 3) {
        int e = j / 3, x = j - e * 3;
        atomicAdd(&agg_coord[(size_t)ri[e] * 3 + x], uu[e] * dif[e][x]);
    }
}

// ---------------------------------------------------------------------------
// Kernel C: h_new = silu(Y + agg_node @ nW1[512:768] + nb1) @ nW2 + nb2
//           pos_new = pos + agg_coord
// ---------------------------------------------------------------------------
__global__ __launch_bounds__(256) void node_kernel(
    const float* __restrict__ X, const float* __restrict__ agg_node,
    const float* __restrict__ agg_coord, const float* __restrict__ pos,
    const float* __restrict__ nW1, const float* __restrict__ nb1,
    const float* __restrict__ nW2, const float* __restrict__ nb2,
    float* __restrict__ out)
{
    __shared__ float t_lds[NB * 256];
    const int n0 = blockIdx.x * NB;
    const int j = threadIdx.x;

    for (int li = j; li < NB * 256; li += 256)
        t_lds[li] = agg_node[(size_t)n0 * 256 + li];
    __syncthreads();

    float acc[NB];
    {
        float b1 = nb1[j];
#pragma unroll
        for (int m = 0; m < NB; ++m)
            acc[m] = X[(size_t)(n0 + m) * 768 + 512 + j] + b1;
        for (int k4 = 0; k4 < 64; ++k4) {
            float w0 = nW1[(size_t)(512 + k4 * 4 + 0) * 256 + j];
            float w1 = nW1[(size_t)(512 + k4 * 4 + 1) * 256 + j];
            float w2 = nW1[(size_t)(512 + k4 * 4 + 2) * 256 + j];
            float w3 = nW1[(size_t)(512 + k4 * 4 + 3) * 256 + j];
#pragma unroll
            for (int m = 0; m < NB; ++m) {
                const float4 g = *reinterpret_cast<const float4*>(&t_lds[m * 256 + k4 * 4]);
                acc[m] = fmaf(g.x, w0, fmaf(g.y, w1, fmaf(g.z, w2, fmaf(g.w, w3, acc[m]))));
            }
        }
    }
    __syncthreads();
#pragma unroll
    for (int m = 0; m < NB; ++m) t_lds[m * 256 + j] = silu_f(acc[m]);
    __syncthreads();
    {
        float b2 = nb2[j];
#pragma unroll
        for (int m = 0; m < NB; ++m) acc[m] = b2;
        for (int k4 = 0; k4 < 64; ++k4) {
            float w0 = nW2[(size_t)(k4 * 4 + 0) * 256 + j];
            float w1 = nW2[(size_t)(k4 * 4 + 1) * 256 + j];
            float w2 = nW2[(size_t)(k4 * 4 + 2) * 256 + j];
            float w3 = nW2[(size_t)(k4 * 4 + 3) * 256 + j];
#pragma unroll
            for (int m = 0; m < NB; ++m) {
                const float4 t = *reinterpret_cast<const float4*>(&t_lds[m * 256 + k4 * 4]);
                acc[m] = fmaf(t.x, w0, fmaf(t.y, w1, fmaf(t.z, w2, fmaf(t.w, w3, acc[m]))));
            }
        }
    }
#pragma unroll
    for (int m = 0; m < NB; ++m)
        out[(size_t)(n0 + m) * 256 + j] = acc[m];

    if (j < NB * 3) {
        int m = j / 3, x = j - m * 3;
        size_t idx = (size_t)(n0 + m) * 3 + x;
        out[(size_t)N_NODES * 256 + idx] = pos[idx] + agg_coord[idx];
    }
}

// ---------------------------------------------------------------------------
extern "C" void kernel_launch(void* const* d_in, const int* in_sizes, int n_in,
                              void* d_out, int out_size, void* d_ws, size_t ws_size,
                              hipStream_t stream)
{
    const float* h     = (const float*)d_in[0];
    const int*   eidx  = (const int*)d_in[1];
    const float* eattr = (const float*)d_in[2];
    const float* pos   = (const float*)d_in[3];
    const float* eW1   = (const float*)d_in[4];
    const float* eb1   = (const float*)d_in[5];
    const float* eW2   = (const float*)d_in[6];
    const float* eb2   = (const float*)d_in[7];
    const float* cW1   = (const float*)d_in[8];
    const float* cb1   = (const float*)d_in[9];
    const float* cW2   = (const float*)d_in[10];
    const float* nW1   = (const float*)d_in[11];
    const float* nb1   = (const float*)d_in[12];
    const float* nW2   = (const float*)d_in[13];
    const float* nb2   = (const float*)d_in[14];
    float* out = (float*)d_out;

    float* X         = (float*)d_ws;                       // N*768 f32
    float* agg_node  = X + (size_t)N_NODES * 768;          // N*256 f32
    float* agg_coord = agg_node + (size_t)N_NODES * 256;   // N*3 f32

    hipMemsetAsync(agg_node, 0,
                   ((size_t)N_NODES * 256 + (size_t)N_NODES * 3) * sizeof(float),
                   stream);

    dim3 gA((N_NODES + 31) / 32, 3);
    precompute_X<<<gA, 256, 0, stream>>>(h, eW1, nW1, X);

    edge_kernel<<<E_EDGES / EB, 256, 0, stream>>>(
        X, pos, eidx, eattr, eW1, eb1, eW2, eb2, cW1, cb1, cW2,
        agg_node, agg_coord);

    node_kernel<<<N_NODES / NB, 256, 0, stream>>>(
        X, agg_node, agg_coord, pos, nW1, nb1, nW2, nb2, out);
}

// Round 2
// 454.286 us; speedup vs baseline: 4.3802x; 4.3802x over previous
//
#include <hip/hip_runtime.h>
#include <hip/hip_bf16.h>

#define N_NODES 10000
#define N_PAD   10016
#define E_EDGES 160000
#define EB 32
#define HID 256

typedef __attribute__((ext_vector_type(4))) float f32x4;
typedef __attribute__((ext_vector_type(8))) short bf16x8;
typedef __attribute__((ext_vector_type(8))) unsigned short u16x8;
typedef unsigned short u16;

__device__ __forceinline__ float silu_f(float x) { return x / (1.0f + __expf(-x)); }

__device__ __forceinline__ u16 f2bf(float f) {           // round-to-nearest-even
    unsigned x = __float_as_uint(f);
    unsigned r = x + 0x7FFFu + ((x >> 16) & 1u);
    return (u16)(r >> 16);
}
__device__ __forceinline__ float bf2f(u16 u) {
    return __uint_as_float(((unsigned)u) << 16);
}
__device__ __forceinline__ f32x4 mfma16(bf16x8 a, bf16x8 b, f32x4 c) {
    return __builtin_amdgcn_mfma_f32_16x16x32_bf16(a, b, c, 0, 0, 0);
}
// swizzled byte offset into a [rows][256] u16 activation tile (stride 512B)
__device__ __forceinline__ int actb(int row, int elem) {
    return (row * 512 + elem * 2) ^ ((row & 7) << 4);
}

// ---------------------------------------------------------------------------
// prep: weight transposes -> bf16 [n][k] layouts
// ---------------------------------------------------------------------------
__global__ __launch_bounds__(256) void prep_weights(
    const float* __restrict__ eW1, const float* __restrict__ eW2,
    const float* __restrict__ cW1, const float* __restrict__ nW1,
    const float* __restrict__ nW2,
    u16* __restrict__ Wt3, u16* __restrict__ e1pt, u16* __restrict__ e2t,
    u16* __restrict__ c1t, u16* __restrict__ n1t, u16* __restrict__ n2t)
{
    const int y = blockIdx.y;
    const float* src; u16* dst; int Ks, Kd;
    switch (y) {
        case 0: src = eW1;                dst = Wt3;                Ks = 512; Kd = 512; break;
        case 1: src = eW1 + 512 * 256;    dst = Wt3 + 256 * 512;    Ks = 512; Kd = 512; break;
        case 2: src = nW1;                dst = Wt3 + 2 * 256 * 512; Ks = 512; Kd = 512; break;
        case 3: src = eW1 + 1024 * 256;   dst = e1pt;               Ks = 52;  Kd = 64;  break; // attr rows + radial row (1075)
        case 4: src = eW2;                dst = e2t;                Ks = 256; Kd = 256; break;
        case 5: src = cW1;                dst = c1t;                Ks = 256; Kd = 256; break;
        case 6: src = nW1 + 512 * 256;    dst = n1t;                Ks = 256; Kd = 256; break;
        default: src = nW2;               dst = n2t;                Ks = 256; Kd = 256; break;
    }
    int idx = blockIdx.x * 256 + threadIdx.x;
    if (idx < 256 * Kd) {
        int n = idx / Kd, k = idx - n * Kd;
        dst[idx] = (k < Ks) ? f2bf(src[(size_t)k * 256 + n]) : (u16)0;
    }
}

// h (f32) -> h_bf (bf16), zero-padded rows to N_PAD
__global__ __launch_bounds__(256) void conv_h(const float* __restrict__ h, u16* __restrict__ hb)
{
    size_t base = ((size_t)blockIdx.x * 256 + threadIdx.x) * 8;
    int row = (int)(base >> 9);
    u16x8 o;
    if (row < N_NODES) {
        const float4 f0 = *(const float4*)&h[base];
        const float4 f1 = *(const float4*)&h[base + 4];
        o[0] = f2bf(f0.x); o[1] = f2bf(f0.y); o[2] = f2bf(f0.z); o[3] = f2bf(f0.w);
        o[4] = f2bf(f1.x); o[5] = f2bf(f1.y); o[6] = f2bf(f1.z); o[7] = f2bf(f1.w);
    } else {
        o = (u16x8)0;
    }
    *(u16x8*)&hb[base] = o;
}

// ---------------------------------------------------------------------------
// Xb[n][0:256]=h@eW1[:512], [256:512]=h@eW1[512:1024], [512:768]=h@nW1[:512] (bf16)
// grid (N_PAD/32, 3), 256 thr
// ---------------------------------------------------------------------------
__global__ __launch_bounds__(256) void precompute_X(
    const u16* __restrict__ hb, const u16* __restrict__ Wt3, u16* __restrict__ Xb)
{
    const int n0b = blockIdx.x * 32;
    const int which = blockIdx.y;
    const int j = threadIdx.x, wv = j >> 6, lane = j & 63;
    const int ml = lane & 15, g = lane >> 4;
    const int n0 = wv * 64;
    const u16* W = Wt3 + (size_t)which * 256 * 512;

    f32x4 acc[2][4];
    const f32x4 z = {0.f, 0.f, 0.f, 0.f};
#pragma unroll
    for (int mt = 0; mt < 2; ++mt)
#pragma unroll
        for (int nt = 0; nt < 4; ++nt) acc[mt][nt] = z;

    for (int kc = 0; kc < 16; ++kc) {
        bf16x8 a0 = *(const bf16x8*)&hb[(size_t)(n0b + ml) * 512 + kc * 32 + g * 8];
        bf16x8 a1 = *(const bf16x8*)&hb[(size_t)(n0b + 16 + ml) * 512 + kc * 32 + g * 8];
#pragma unroll
        for (int nt = 0; nt < 4; ++nt) {
            bf16x8 b = *(const bf16x8*)&W[(size_t)(n0 + nt * 16 + ml) * 512 + kc * 32 + g * 8];
            acc[0][nt] = mfma16(a0, b, acc[0][nt]);
            acc[1][nt] = mfma16(a1, b, acc[1][nt]);
        }
    }
#pragma unroll
    for (int mt = 0; mt < 2; ++mt)
#pragma unroll
        for (int nt = 0; nt < 4; ++nt) {
            int col = n0 + nt * 16 + ml;
#pragma unroll
            for (int i = 0; i < 4; ++i) {
                int row = n0b + mt * 16 + g * 4 + i;
                Xb[(size_t)row * 768 + which * 256 + col] = f2bf(acc[mt][nt][i]);
            }
        }
}

// ---------------------------------------------------------------------------
// edge kernel: 32 edges/block, 4 waves, MFMA stages + atomic aggregation
// ---------------------------------------------------------------------------
__global__ __launch_bounds__(256) void edge_kernel(
    const u16* __restrict__ Xb, const float* __restrict__ pos,
    const int* __restrict__ eidx, const float* __restrict__ eattr,
    const u16* __restrict__ e1pt, const float* __restrict__ eb1,
    const u16* __restrict__ e2t, const float* __restrict__ eb2,
    const u16* __restrict__ c1t, const float* __restrict__ cb1,
    const float* __restrict__ cW2,
    float* __restrict__ agg_node, float* __restrict__ agg_coord)
{
    __shared__ u16 attr[EB * 64];    // swizzled, stride 128B
    __shared__ u16 act1[EB * 256];   // swizzled, stride 512B
    __shared__ u16 act2[EB * 256];
    __shared__ int ri[EB], ci[EB];
    __shared__ float dif[EB][3];
    __shared__ float rad[EB];
    __shared__ float red[4 * EB];

    const int e0 = blockIdx.x * EB;
    const int j = threadIdx.x, wv = j >> 6, lane = j & 63;
    const int ml = lane & 15, g = lane >> 4;
    const int n0 = wv * 64;
    const f32x4 z = {0.f, 0.f, 0.f, 0.f};

    if (j < EB) {
        int e = e0 + j;
        int r = eidx[e], c = eidx[E_EDGES + e];
        ri[j] = r; ci[j] = c;
        float dx = pos[r * 3 + 0] - pos[c * 3 + 0];
        float dy = pos[r * 3 + 1] - pos[c * 3 + 1];
        float dz = pos[r * 3 + 2] - pos[c * 3 + 2];
        dif[j][0] = dx; dif[j][1] = dy; dif[j][2] = dz;
        rad[j] = sqrtf(dx * dx + dy * dy + dz * dz) + 1e-8f;
    }
    __syncthreads();
    for (int li = j; li < EB * 64; li += 256) {
        int row = li >> 6, k = li & 63;
        float v = (k < 51) ? eattr[(size_t)(e0 + row) * 51 + k] : (k == 51 ? rad[row] : 0.f);
        int byte = (row * 128 + k * 2) ^ ((row & 7) << 4);
        attr[byte >> 1] = f2bf(v);
    }
    __syncthreads();

    f32x4 acc[2][4];

    // ---- stage 1: attr/radial MFMA (K=64) + bias + Xr/Xc gather, silu -> act1
#pragma unroll
    for (int mt = 0; mt < 2; ++mt)
#pragma unroll
        for (int nt = 0; nt < 4; ++nt) acc[mt][nt] = z;
#pragma unroll
    for (int kc = 0; kc < 2; ++kc) {
        bf16x8 a0 = *(const bf16x8*)((const char*)attr + ((ml * 128 + (kc * 32 + g * 8) * 2) ^ ((ml & 7) << 4)));
        bf16x8 a1 = *(const bf16x8*)((const char*)attr + (((16 + ml) * 128 + (kc * 32 + g * 8) * 2) ^ ((ml & 7) << 4)));
#pragma unroll
        for (int nt = 0; nt < 4; ++nt) {
            bf16x8 b = *(const bf16x8*)&e1pt[(size_t)(n0 + nt * 16 + ml) * 64 + kc * 32 + g * 8];
            acc[0][nt] = mfma16(a0, b, acc[0][nt]);
            acc[1][nt] = mfma16(a1, b, acc[1][nt]);
        }
    }
#pragma unroll
    for (int mt = 0; mt < 2; ++mt)
#pragma unroll
        for (int nt = 0; nt < 4; ++nt) {
            int col = n0 + nt * 16 + ml;
            float b1 = eb1[col];
#pragma unroll
            for (int i = 0; i < 4; ++i) {
                int m = mt * 16 + g * 4 + i;
                float v = acc[mt][nt][i] + b1
                        + bf2f(Xb[(size_t)ri[m] * 768 + col])
                        + bf2f(Xb[(size_t)ci[m] * 768 + 256 + col]);
                act1[actb(m, col) >> 1] = f2bf(silu_f(v));
            }
        }
    __syncthreads();

    // ---- stage 2: e = silu(act1 @ eW2 + eb2) -> act2, atomic agg_node
#pragma unroll
    for (int mt = 0; mt < 2; ++mt)
#pragma unroll
        for (int nt = 0; nt < 4; ++nt) acc[mt][nt] = z;
    for (int kc = 0; kc < 8; ++kc) {
        bf16x8 a0 = *(const bf16x8*)((const char*)act1 + actb(ml, kc * 32 + g * 8));
        bf16x8 a1 = *(const bf16x8*)((const char*)act1 + actb(16 + ml, kc * 32 + g * 8));
#pragma unroll
        for (int nt = 0; nt < 4; ++nt) {
            bf16x8 b = *(const bf16x8*)&e2t[(size_t)(n0 + nt * 16 + ml) * 256 + kc * 32 + g * 8];
            acc[0][nt] = mfma16(a0, b, acc[0][nt]);
            acc[1][nt] = mfma16(a1, b, acc[1][nt]);
        }
    }
#pragma unroll
    for (int mt = 0; mt < 2; ++mt)
#pragma unroll
        for (int nt = 0; nt < 4; ++nt) {
            int col = n0 + nt * 16 + ml;
            float b2 = eb2[col];
#pragma unroll
            for (int i = 0; i < 4; ++i) {
                int m = mt * 16 + g * 4 + i;
                float v = silu_f(acc[mt][nt][i] + b2);
                act2[actb(m, col) >> 1] = f2bf(v);
                atomicAdd(&agg_node[(size_t)ri[m] * 256 + col], v);
            }
        }
    __syncthreads();

    // ---- stage 3: u = clip((silu(act2 @ cW1 + cb1)) . cW2), coord atomics
#pragma unroll
    for (int mt = 0; mt < 2; ++mt)
#pragma unroll
        for (int nt = 0; nt < 4; ++nt) acc[mt][nt] = z;
    for (int kc = 0; kc < 8; ++kc) {
        bf16x8 a0 = *(const bf16x8*)((const char*)act2 + actb(ml, kc * 32 + g * 8));
        bf16x8 a1 = *(const bf16x8*)((const char*)act2 + actb(16 + ml, kc * 32 + g * 8));
#pragma unroll
        for (int nt = 0; nt < 4; ++nt) {
            bf16x8 b = *(const bf16x8*)&c1t[(size_t)(n0 + nt * 16 + ml) * 256 + kc * 32 + g * 8];
            acc[0][nt] = mfma16(a0, b, acc[0][nt]);
            acc[1][nt] = mfma16(a1, b, acc[1][nt]);
        }
    }
    float p[2][4] = {{0.f, 0.f, 0.f, 0.f}, {0.f, 0.f, 0.f, 0.f}};
#pragma unroll
    for (int mt = 0; mt < 2; ++mt)
#pragma unroll
        for (int nt = 0; nt < 4; ++nt) {
            int col = n0 + nt * 16 + ml;
            float b3 = cb1[col];
            float w2 = cW2[col];
#pragma unroll
            for (int i = 0; i < 4; ++i)
                p[mt][i] += silu_f(acc[mt][nt][i] + b3) * w2;
        }
#pragma unroll
    for (int mt = 0; mt < 2; ++mt)
#pragma unroll
        for (int i = 0; i < 4; ++i) {
            float v = p[mt][i];
            v += __shfl_xor(v, 1);
            v += __shfl_xor(v, 2);
            v += __shfl_xor(v, 4);
            v += __shfl_xor(v, 8);
            p[mt][i] = v;
        }
    if (ml == 0) {
#pragma unroll
        for (int mt = 0; mt < 2; ++mt)
#pragma unroll
            for (int i = 0; i < 4; ++i)
                red[wv * EB + mt * 16 + g * 4 + i] = p[mt][i];
    }
    __syncthreads();
    if (j < EB) {
        float u = red[j] + red[EB + j] + red[2 * EB + j] + red[3 * EB + j];
        u = fminf(fmaxf(u, -1.f), 1.f);
        int r = ri[j];
        atomicAdd(&agg_coord[(size_t)r * 3 + 0], u * dif[j][0]);
        atomicAdd(&agg_coord[(size_t)r * 3 + 1], u * dif[j][1]);
        atomicAdd(&agg_coord[(size_t)r * 3 + 2], u * dif[j][2]);
    }
}

// ---------------------------------------------------------------------------
// node kernel: h_new = silu([h,agg] @ nW1 + nb1) @ nW2 + nb2 ; pos update
// ---------------------------------------------------------------------------
__global__ __launch_bounds__(256) void node_kernel(
    const u16* __restrict__ Xb, const float* __restrict__ agg_node,
    const float* __restrict__ agg_coord, const float* __restrict__ pos,
    const u16* __restrict__ n1t, const float* __restrict__ nb1,
    const u16* __restrict__ n2t, const float* __restrict__ nb2,
    float* __restrict__ out)
{
    __shared__ u16 act1[32 * 256];
    __shared__ u16 act2[32 * 256];
    const int n0b = blockIdx.x * 32;
    const int j = threadIdx.x, wv = j >> 6, lane = j & 63;
    const int ml = lane & 15, g = lane >> 4;
    const int n0 = wv * 64;
    const f32x4 z = {0.f, 0.f, 0.f, 0.f};

    for (int li = j; li < 32 * 256; li += 256) {
        int r = li >> 8, c = li & 255;
        act1[actb(r, c) >> 1] = f2bf(agg_node[(size_t)(n0b + r) * 256 + c]);
    }
    __syncthreads();

    f32x4 acc[2][4];
#pragma unroll
    for (int mt = 0; mt < 2; ++mt)
#pragma unroll
        for (int nt = 0; nt < 4; ++nt) acc[mt][nt] = z;
    for (int kc = 0; kc < 8; ++kc) {
        bf16x8 a0 = *(const bf16x8*)((const char*)act1 + actb(ml, kc * 32 + g * 8));
        bf16x8 a1 = *(const bf16x8*)((const char*)act1 + actb(16 + ml, kc * 32 + g * 8));
#pragma unroll
        for (int nt = 0; nt < 4; ++nt) {
            bf16x8 b = *(const bf16x8*)&n1t[(size_t)(n0 + nt * 16 + ml) * 256 + kc * 32 + g * 8];
            acc[0][nt] = mfma16(a0, b, acc[0][nt]);
            acc[1][nt] = mfma16(a1, b, acc[1][nt]);
        }
    }
#pragma unroll
    for (int mt = 0; mt < 2; ++mt)
#pragma unroll
        for (int nt = 0; nt < 4; ++nt) {
            int col = n0 + nt * 16 + ml;
            float b1 = nb1[col];
#pragma unroll
            for (int i = 0; i < 4; ++i) {
                int m = mt * 16 + g * 4 + i;
                float v = acc[mt][nt][i] + b1 + bf2f(Xb[(size_t)(n0b + m) * 768 + 512 + col]);
                act2[actb(m, col) >> 1] = f2bf(silu_f(v));
            }
        }
    __syncthreads();
#pragma unroll
    for (int mt = 0; mt < 2; ++mt)
#pragma unroll
        for (int nt = 0; nt < 4; ++nt) acc[mt][nt] = z;
    for (int kc = 0; kc < 8; ++kc) {
        bf16x8 a0 = *(const bf16x8*)((const char*)act2 + actb(ml, kc * 32 + g * 8));
        bf16x8 a1 = *(const bf16x8*)((const char*)act2 + actb(16 + ml, kc * 32 + g * 8));
#pragma unroll
        for (int nt = 0; nt < 4; ++nt) {
            bf16x8 b = *(const bf16x8*)&n2t[(size_t)(n0 + nt * 16 + ml) * 256 + kc * 32 + g * 8];
            acc[0][nt] = mfma16(a0, b, acc[0][nt]);
            acc[1][nt] = mfma16(a1, b, acc[1][nt]);
        }
    }
#pragma unroll
    for (int mt = 0; mt < 2; ++mt)
#pragma unroll
        for (int nt = 0; nt < 4; ++nt) {
            int col = n0 + nt * 16 + ml;
            float b2 = nb2[col];
#pragma unroll
            for (int i = 0; i < 4; ++i) {
                int row = n0b + mt * 16 + g * 4 + i;
                if (row < N_NODES)
                    out[(size_t)row * 256 + col] = acc[mt][nt][i] + b2;
            }
        }
    if (j < 96) {
        int idx = n0b * 3 + j;
        if (idx < N_NODES * 3)
            out[(size_t)N_NODES * 256 + idx] = pos[idx] + agg_coord[idx];
    }
}

// ---------------------------------------------------------------------------
extern "C" void kernel_launch(void* const* d_in, const int* in_sizes, int n_in,
                              void* d_out, int out_size, void* d_ws, size_t ws_size,
                              hipStream_t stream)
{
    (void)in_sizes; (void)n_in; (void)out_size; (void)ws_size;
    const float* h     = (const float*)d_in[0];
    const int*   eidx  = (const int*)d_in[1];
    const float* eattr = (const float*)d_in[2];
    const float* pos   = (const float*)d_in[3];
    const float* eW1   = (const float*)d_in[4];
    const float* eb1   = (const float*)d_in[5];
    const float* eW2   = (const float*)d_in[6];
    const float* eb2   = (const float*)d_in[7];
    const float* cW1   = (const float*)d_in[8];
    const float* cb1   = (const float*)d_in[9];
    const float* cW2   = (const float*)d_in[10];
    const float* nW1   = (const float*)d_in[11];
    const float* nb1   = (const float*)d_in[12];
    const float* nW2   = (const float*)d_in[13];
    const float* nb2   = (const float*)d_in[14];
    float* out = (float*)d_out;

    u16* Xb   = (u16*)d_ws;                                  // N_PAD*768 bf16
    u16* hb   = Xb + (size_t)N_PAD * 768;                    // N_PAD*512
    u16* Wt3  = hb + (size_t)N_PAD * 512;                    // 3*256*512
    u16* e1pt = Wt3 + 3 * 256 * 512;                         // 256*64
    u16* e2t  = e1pt + 256 * 64;                             // 256*256
    u16* c1t  = e2t + 256 * 256;
    u16* n1t  = c1t + 256 * 256;
    u16* n2t  = n1t + 256 * 256;
    float* agg_node  = (float*)(n2t + 256 * 256);            // N_PAD*256 f32
    float* agg_coord = agg_node + (size_t)N_PAD * 256;       // N_PAD*3  f32

    hipMemsetAsync(agg_node, 0, (size_t)N_PAD * 259 * sizeof(float), stream);

    prep_weights<<<dim3(512, 8), 256, 0, stream>>>(eW1, eW2, cW1, nW1, nW2,
                                                   Wt3, e1pt, e2t, c1t, n1t, n2t);
    conv_h<<<(N_PAD * 512 / 8) / 256, 256, 0, stream>>>(h, hb);

    precompute_X<<<dim3(N_PAD / 32, 3), 256, 0, stream>>>(hb, Wt3, Xb);

    edge_kernel<<<E_EDGES / EB, 256, 0, stream>>>(
        Xb, pos, eidx, eattr, e1pt, eb1, e2t, eb2, c1t, cb1, cW2,
        agg_node, agg_coord);

    node_kernel<<<N_PAD / 32, 256, 0, stream>>>(
        Xb, agg_node, agg_coord, pos, n1t, nb1, n2t, nb2, out);
}

// Round 3
// 397.288 us; speedup vs baseline: 5.0086x; 1.1435x over previous
//
#include <hip/hip_runtime.h>
#include <hip/hip_bf16.h>

#define N_NODES 10000
#define N_PAD   10016
#define E_EDGES 160000
#define EB 32
#define HID 256

typedef __attribute__((ext_vector_type(4))) float f32x4;
typedef __attribute__((ext_vector_type(8))) short bf16x8;
typedef __attribute__((ext_vector_type(8))) unsigned short u16x8;
typedef unsigned short u16;

__device__ __forceinline__ float silu_f(float x) { return x / (1.0f + __expf(-x)); }

__device__ __forceinline__ u16 f2bf(float f) {           // round-to-nearest-even
    unsigned x = __float_as_uint(f);
    unsigned r = x + 0x7FFFu + ((x >> 16) & 1u);
    return (u16)(r >> 16);
}
__device__ __forceinline__ float bf2f(u16 u) {
    return __uint_as_float(((unsigned)u) << 16);
}
__device__ __forceinline__ f32x4 mfma16(bf16x8 a, bf16x8 b, f32x4 c) {
    return __builtin_amdgcn_mfma_f32_16x16x32_bf16(a, b, c, 0, 0, 0);
}
// swizzled byte offset into a [rows][256] u16 activation tile (stride 512B)
__device__ __forceinline__ int actb(int row, int elem) {
    return (row * 512 + elem * 2) ^ ((row & 7) << 4);
}

// ---------------------------------------------------------------------------
// prep: weight transposes -> bf16 [n][k] layouts
// ---------------------------------------------------------------------------
__global__ __launch_bounds__(256) void prep_weights(
    const float* __restrict__ eW1, const float* __restrict__ eW2,
    const float* __restrict__ cW1, const float* __restrict__ nW1,
    const float* __restrict__ nW2,
    u16* __restrict__ Wt3, u16* __restrict__ e1pt, u16* __restrict__ e2t,
    u16* __restrict__ c1t, u16* __restrict__ n1t, u16* __restrict__ n2t)
{
    const int y = blockIdx.y;
    const float* src; u16* dst; int Ks, Kd;
    switch (y) {
        case 0: src = eW1;                dst = Wt3;                Ks = 512; Kd = 512; break;
        case 1: src = eW1 + 512 * 256;    dst = Wt3 + 256 * 512;    Ks = 512; Kd = 512; break;
        case 2: src = nW1;                dst = Wt3 + 2 * 256 * 512; Ks = 512; Kd = 512; break;
        case 3: src = eW1 + 1024 * 256;   dst = e1pt;               Ks = 52;  Kd = 64;  break; // attr rows + radial row (1075)
        case 4: src = eW2;                dst = e2t;                Ks = 256; Kd = 256; break;
        case 5: src = cW1;                dst = c1t;                Ks = 256; Kd = 256; break;
        case 6: src = nW1 + 512 * 256;    dst = n1t;                Ks = 256; Kd = 256; break;
        default: src = nW2;               dst = n2t;                Ks = 256; Kd = 256; break;
    }
    int idx = blockIdx.x * 256 + threadIdx.x;
    if (idx < 256 * Kd) {
        int n = idx / Kd, k = idx - n * Kd;
        dst[idx] = (k < Ks) ? f2bf(src[(size_t)k * 256 + n]) : (u16)0;
    }
}

// h (f32) -> h_bf (bf16), zero-padded rows to N_PAD
__global__ __launch_bounds__(256) void conv_h(const float* __restrict__ h, u16* __restrict__ hb)
{
    size_t base = ((size_t)blockIdx.x * 256 + threadIdx.x) * 8;
    int row = (int)(base >> 9);
    u16x8 o;
    if (row < N_NODES) {
        const float4 f0 = *(const float4*)&h[base];
        const float4 f1 = *(const float4*)&h[base + 4];
        o[0] = f2bf(f0.x); o[1] = f2bf(f0.y); o[2] = f2bf(f0.z); o[3] = f2bf(f0.w);
        o[4] = f2bf(f1.x); o[5] = f2bf(f1.y); o[6] = f2bf(f1.z); o[7] = f2bf(f1.w);
    } else {
        o = (u16x8)0;
    }
    *(u16x8*)&hb[base] = o;
}

// ---------------------------------------------------------------------------
// Xb[n][0:256]=h@eW1[:512], [256:512]=h@eW1[512:1024], [512:768]=h@nW1[:512] (bf16)
// ---------------------------------------------------------------------------
__global__ __launch_bounds__(256) void precompute_X(
    const u16* __restrict__ hb, const u16* __restrict__ Wt3, u16* __restrict__ Xb)
{
    const int n0b = blockIdx.x * 32;
    const int which = blockIdx.y;
    const int j = threadIdx.x, wv = j >> 6, lane = j & 63;
    const int ml = lane & 15, g = lane >> 4;
    const int n0 = wv * 64;
    const u16* W = Wt3 + (size_t)which * 256 * 512;

    f32x4 acc[2][4];
    const f32x4 z = {0.f, 0.f, 0.f, 0.f};
#pragma unroll
    for (int mt = 0; mt < 2; ++mt)
#pragma unroll
        for (int nt = 0; nt < 4; ++nt) acc[mt][nt] = z;

    for (int kc = 0; kc < 16; ++kc) {
        bf16x8 a0 = *(const bf16x8*)&hb[(size_t)(n0b + ml) * 512 + kc * 32 + g * 8];
        bf16x8 a1 = *(const bf16x8*)&hb[(size_t)(n0b + 16 + ml) * 512 + kc * 32 + g * 8];
#pragma unroll
        for (int nt = 0; nt < 4; ++nt) {
            bf16x8 b = *(const bf16x8*)&W[(size_t)(n0 + nt * 16 + ml) * 512 + kc * 32 + g * 8];
            acc[0][nt] = mfma16(a0, b, acc[0][nt]);
            acc[1][nt] = mfma16(a1, b, acc[1][nt]);
        }
    }
#pragma unroll
    for (int mt = 0; mt < 2; ++mt)
#pragma unroll
        for (int nt = 0; nt < 4; ++nt) {
            int col = n0 + nt * 16 + ml;
#pragma unroll
            for (int i = 0; i < 4; ++i) {
                int row = n0b + mt * 16 + g * 4 + i;
                Xb[(size_t)row * 768 + which * 256 + col] = f2bf(acc[mt][nt][i]);
            }
        }
}

// ---------------------------------------------------------------------------
// edge kernel: 32 edges/block, 4 waves. Cooperative wide gather of Xr+Xc
// into LDS (bufA), then 3 MFMA stages. bufA is reused for act2.
// ---------------------------------------------------------------------------
__global__ __launch_bounds__(256) void edge_kernel(
    const u16* __restrict__ Xb, const float* __restrict__ pos,
    const int* __restrict__ eidx, const float* __restrict__ eattr,
    const u16* __restrict__ e1pt, const float* __restrict__ eb1,
    const u16* __restrict__ e2t, const float* __restrict__ eb2,
    const u16* __restrict__ c1t, const float* __restrict__ cb1,
    const float* __restrict__ cW2,
    float* __restrict__ agg_node, float* __restrict__ agg_coord)
{
    __shared__ u16 attr[EB * 64];    // swizzled, stride 128B
    __shared__ u16 bufA[EB * 256];   // xsum (Xr+Xc), later act2 (swizzled)
    __shared__ u16 bufB[EB * 256];   // act1 (swizzled)
    __shared__ int ri[EB], ci[EB];
    __shared__ float dif[EB][3];
    __shared__ float rad[EB];
    __shared__ float red[4 * EB];

    const int e0 = blockIdx.x * EB;
    const int j = threadIdx.x, wv = j >> 6, lane = j & 63;
    const int ml = lane & 15, g = lane >> 4;
    const int n0 = wv * 64;
    const f32x4 z = {0.f, 0.f, 0.f, 0.f};

    if (j < EB) {
        int e = e0 + j;
        int r = eidx[e], c = eidx[E_EDGES + e];
        ri[j] = r; ci[j] = c;
        float dx = pos[r * 3 + 0] - pos[c * 3 + 0];
        float dy = pos[r * 3 + 1] - pos[c * 3 + 1];
        float dz = pos[r * 3 + 2] - pos[c * 3 + 2];
        dif[j][0] = dx; dif[j][1] = dy; dif[j][2] = dz;
        rad[j] = sqrtf(dx * dx + dy * dy + dz * dz) + 1e-8f;
    }
    __syncthreads();

    // ---- cooperative wide gather: bufA[e][:] = Xr[ri[e]] + Xc[ci[e]] (bf16)
#pragma unroll
    for (int t = 0; t < 4; ++t) {
        int li = t * 256 + j;           // (edge, 16B-chunk)
        int e = li >> 5, c = li & 31;
        const u16x8 xr = *(const u16x8*)&Xb[(size_t)ri[e] * 768 + c * 8];
        const u16x8 xc = *(const u16x8*)&Xb[(size_t)ci[e] * 768 + 256 + c * 8];
        u16x8 o;
#pragma unroll
        for (int k = 0; k < 8; ++k) o[k] = f2bf(bf2f(xr[k]) + bf2f(xc[k]));
        *(u16x8*)((char*)bufA + ((e * 512 + c * 16) ^ ((e & 7) << 4))) = o;
    }
    // ---- stage edge_attr (+radial in col 51)
    for (int li = j; li < EB * 64; li += 256) {
        int row = li >> 6, k = li & 63;
        float v = (k < 51) ? eattr[(size_t)(e0 + row) * 51 + k] : (k == 51 ? rad[row] : 0.f);
        int byte = (row * 128 + k * 2) ^ ((row & 7) << 4);
        attr[byte >> 1] = f2bf(v);
    }
    __syncthreads();

    f32x4 acc[2][4];

    // ---- stage 1: attr/radial MFMA (K=64) + bias + xsum, silu -> bufB
#pragma unroll
    for (int mt = 0; mt < 2; ++mt)
#pragma unroll
        for (int nt = 0; nt < 4; ++nt) acc[mt][nt] = z;
#pragma unroll
    for (int kc = 0; kc < 2; ++kc) {
        bf16x8 a0 = *(const bf16x8*)((const char*)attr + ((ml * 128 + (kc * 32 + g * 8) * 2) ^ ((ml & 7) << 4)));
        bf16x8 a1 = *(const bf16x8*)((const char*)attr + (((16 + ml) * 128 + (kc * 32 + g * 8) * 2) ^ ((ml & 7) << 4)));
#pragma unroll
        for (int nt = 0; nt < 4; ++nt) {
            bf16x8 b = *(const bf16x8*)&e1pt[(size_t)(n0 + nt * 16 + ml) * 64 + kc * 32 + g * 8];
            acc[0][nt] = mfma16(a0, b, acc[0][nt]);
            acc[1][nt] = mfma16(a1, b, acc[1][nt]);
        }
    }
#pragma unroll
    for (int mt = 0; mt < 2; ++mt)
#pragma unroll
        for (int nt = 0; nt < 4; ++nt) {
            int col = n0 + nt * 16 + ml;
            float b1 = eb1[col];
#pragma unroll
            for (int i = 0; i < 4; ++i) {
                int m = mt * 16 + g * 4 + i;
                float v = acc[mt][nt][i] + b1 + bf2f(bufA[actb(m, col) >> 1]);
                bufB[actb(m, col) >> 1] = f2bf(silu_f(v));
            }
        }
    __syncthreads();

    // ---- stage 2: e = silu(bufB @ eW2 + eb2) -> bufA, atomic agg_node
#pragma unroll
    for (int mt = 0; mt < 2; ++mt)
#pragma unroll
        for (int nt = 0; nt < 4; ++nt) acc[mt][nt] = z;
    for (int kc = 0; kc < 8; ++kc) {
        bf16x8 a0 = *(const bf16x8*)((const char*)bufB + actb(ml, kc * 32 + g * 8));
        bf16x8 a1 = *(const bf16x8*)((const char*)bufB + actb(16 + ml, kc * 32 + g * 8));
#pragma unroll
        for (int nt = 0; nt < 4; ++nt) {
            bf16x8 b = *(const bf16x8*)&e2t[(size_t)(n0 + nt * 16 + ml) * 256 + kc * 32 + g * 8];
            acc[0][nt] = mfma16(a0, b, acc[0][nt]);
            acc[1][nt] = mfma16(a1, b, acc[1][nt]);
        }
    }
#pragma unroll
    for (int mt = 0; mt < 2; ++mt)
#pragma unroll
        for (int nt = 0; nt < 4; ++nt) {
            int col = n0 + nt * 16 + ml;
            float b2 = eb2[col];
#pragma unroll
            for (int i = 0; i < 4; ++i) {
                int m = mt * 16 + g * 4 + i;
                float v = silu_f(acc[mt][nt][i] + b2);
                bufA[actb(m, col) >> 1] = f2bf(v);
                atomicAdd(&agg_node[(size_t)ri[m] * 256 + col], v);
            }
        }
    __syncthreads();

    // ---- stage 3: u = clip((silu(bufA @ cW1 + cb1)) . cW2), coord atomics
#pragma unroll
    for (int mt = 0; mt < 2; ++mt)
#pragma unroll
        for (int nt = 0; nt < 4; ++nt) acc[mt][nt] = z;
    for (int kc = 0; kc < 8; ++kc) {
        bf16x8 a0 = *(const bf16x8*)((const char*)bufA + actb(ml, kc * 32 + g * 8));
        bf16x8 a1 = *(const bf16x8*)((const char*)bufA + actb(16 + ml, kc * 32 + g * 8));
#pragma unroll
        for (int nt = 0; nt < 4; ++nt) {
            bf16x8 b = *(const bf16x8*)&c1t[(size_t)(n0 + nt * 16 + ml) * 256 + kc * 32 + g * 8];
            acc[0][nt] = mfma16(a0, b, acc[0][nt]);
            acc[1][nt] = mfma16(a1, b, acc[1][nt]);
        }
    }
    float p[2][4] = {{0.f, 0.f, 0.f, 0.f}, {0.f, 0.f, 0.f, 0.f}};
#pragma unroll
    for (int mt = 0; mt < 2; ++mt)
#pragma unroll
        for (int nt = 0; nt < 4; ++nt) {
            int col = n0 + nt * 16 + ml;
            float b3 = cb1[col];
            float w2 = cW2[col];
#pragma unroll
            for (int i = 0; i < 4; ++i)
                p[mt][i] += silu_f(acc[mt][nt][i] + b3) * w2;
        }
#pragma unroll
    for (int mt = 0; mt < 2; ++mt)
#pragma unroll
        for (int i = 0; i < 4; ++i) {
            float v = p[mt][i];
            v += __shfl_xor(v, 1);
            v += __shfl_xor(v, 2);
            v += __shfl_xor(v, 4);
            v += __shfl_xor(v, 8);
            p[mt][i] = v;
        }
    if (ml == 0) {
#pragma unroll
        for (int mt = 0; mt < 2; ++mt)
#pragma unroll
            for (int i = 0; i < 4; ++i)
                red[wv * EB + mt * 16 + g * 4 + i] = p[mt][i];
    }
    __syncthreads();
    if (j < EB) {
        float u = red[j] + red[EB + j] + red[2 * EB + j] + red[3 * EB + j];
        u = fminf(fmaxf(u, -1.f), 1.f);
        int r = ri[j];
        atomicAdd(&agg_coord[(size_t)r * 3 + 0], u * dif[j][0]);
        atomicAdd(&agg_coord[(size_t)r * 3 + 1], u * dif[j][1]);
        atomicAdd(&agg_coord[(size_t)r * 3 + 2], u * dif[j][2]);
    }
}

// ---------------------------------------------------------------------------
// node kernel: h_new = silu([h,agg] @ nW1 + nb1) @ nW2 + nb2 ; pos update
// ---------------------------------------------------------------------------
__global__ __launch_bounds__(256) void node_kernel(
    const u16* __restrict__ Xb, const float* __restrict__ agg_node,
    const float* __restrict__ agg_coord, const float* __restrict__ pos,
    const u16* __restrict__ n1t, const float* __restrict__ nb1,
    const u16* __restrict__ n2t, const float* __restrict__ nb2,
    float* __restrict__ out)
{
    __shared__ u16 act1[32 * 256];
    __shared__ u16 act2[32 * 256];
    const int n0b = blockIdx.x * 32;
    const int j = threadIdx.x, wv = j >> 6, lane = j & 63;
    const int ml = lane & 15, g = lane >> 4;
    const int n0 = wv * 64;
    const f32x4 z = {0.f, 0.f, 0.f, 0.f};

    for (int li = j; li < 32 * 256; li += 256) {
        int r = li >> 8, c = li & 255;
        act1[actb(r, c) >> 1] = f2bf(agg_node[(size_t)(n0b + r) * 256 + c]);
    }
    __syncthreads();

    f32x4 acc[2][4];
#pragma unroll
    for (int mt = 0; mt < 2; ++mt)
#pragma unroll
        for (int nt = 0; nt < 4; ++nt) acc[mt][nt] = z;
    for (int kc = 0; kc < 8; ++kc) {
        bf16x8 a0 = *(const bf16x8*)((const char*)act1 + actb(ml, kc * 32 + g * 8));
        bf16x8 a1 = *(const bf16x8*)((const char*)act1 + actb(16 + ml, kc * 32 + g * 8));
#pragma unroll
        for (int nt = 0; nt < 4; ++nt) {
            bf16x8 b = *(const bf16x8*)&n1t[(size_t)(n0 + nt * 16 + ml) * 256 + kc * 32 + g * 8];
            acc[0][nt] = mfma16(a0, b, acc[0][nt]);
            acc[1][nt] = mfma16(a1, b, acc[1][nt]);
        }
    }
#pragma unroll
    for (int mt = 0; mt < 2; ++mt)
#pragma unroll
        for (int nt = 0; nt < 4; ++nt) {
            int col = n0 + nt * 16 + ml;
            float b1 = nb1[col];
#pragma unroll
            for (int i = 0; i < 4; ++i) {
                int m = mt * 16 + g * 4 + i;
                float v = acc[mt][nt][i] + b1 + bf2f(Xb[(size_t)(n0b + m) * 768 + 512 + col]);
                act2[actb(m, col) >> 1] = f2bf(silu_f(v));
            }
        }
    __syncthreads();
#pragma unroll
    for (int mt = 0; mt < 2; ++mt)
#pragma unroll
        for (int nt = 0; nt < 4; ++nt) acc[mt][nt] = z;
    for (int kc = 0; kc < 8; ++kc) {
        bf16x8 a0 = *(const bf16x8*)((const char*)act2 + actb(ml, kc * 32 + g * 8));
        bf16x8 a1 = *(const bf16x8*)((const char*)act2 + actb(16 + ml, kc * 32 + g * 8));
#pragma unroll
        for (int nt = 0; nt < 4; ++nt) {
            bf16x8 b = *(const bf16x8*)&n2t[(size_t)(n0 + nt * 16 + ml) * 256 + kc * 32 + g * 8];
            acc[0][nt] = mfma16(a0, b, acc[0][nt]);
            acc[1][nt] = mfma16(a1, b, acc[1][nt]);
        }
    }
#pragma unroll
    for (int mt = 0; mt < 2; ++mt)
#pragma unroll
        for (int nt = 0; nt < 4; ++nt) {
            int col = n0 + nt * 16 + ml;
            float b2 = nb2[col];
#pragma unroll
            for (int i = 0; i < 4; ++i) {
                int row = n0b + mt * 16 + g * 4 + i;
                if (row < N_NODES)
                    out[(size_t)row * 256 + col] = acc[mt][nt][i] + b2;
            }
        }
    if (j < 96) {
        int idx = n0b * 3 + j;
        if (idx < N_NODES * 3)
            out[(size_t)N_NODES * 256 + idx] = pos[idx] + agg_coord[idx];
    }
}

// ---------------------------------------------------------------------------
extern "C" void kernel_launch(void* const* d_in, const int* in_sizes, int n_in,
                              void* d_out, int out_size, void* d_ws, size_t ws_size,
                              hipStream_t stream)
{
    (void)in_sizes; (void)n_in; (void)out_size; (void)ws_size;
    const float* h     = (const float*)d_in[0];
    const int*   eidx  = (const int*)d_in[1];
    const float* eattr = (const float*)d_in[2];
    const float* pos   = (const float*)d_in[3];
    const float* eW1   = (const float*)d_in[4];
    const float* eb1   = (const float*)d_in[5];
    const float* eW2   = (const float*)d_in[6];
    const float* eb2   = (const float*)d_in[7];
    const float* cW1   = (const float*)d_in[8];
    const float* cb1   = (const float*)d_in[9];
    const float* cW2   = (const float*)d_in[10];
    const float* nW1   = (const float*)d_in[11];
    const float* nb1   = (const float*)d_in[12];
    const float* nW2   = (const float*)d_in[13];
    const float* nb2   = (const float*)d_in[14];
    float* out = (float*)d_out;

    u16* Xb   = (u16*)d_ws;                                  // N_PAD*768 bf16
    u16* hb   = Xb + (size_t)N_PAD * 768;                    // N_PAD*512
    u16* Wt3  = hb + (size_t)N_PAD * 512;                    // 3*256*512
    u16* e1pt = Wt3 + 3 * 256 * 512;                         // 256*64
    u16* e2t  = e1pt + 256 * 64;                             // 256*256
    u16* c1t  = e2t + 256 * 256;
    u16* n1t  = c1t + 256 * 256;
    u16* n2t  = n1t + 256 * 256;
    float* agg_node  = (float*)(n2t + 256 * 256);            // N_PAD*256 f32
    float* agg_coord = agg_node + (size_t)N_PAD * 256;       // N_PAD*3  f32

    hipMemsetAsync(agg_node, 0, (size_t)N_PAD * 259 * sizeof(float), stream);

    prep_weights<<<dim3(512, 8), 256, 0, stream>>>(eW1, eW2, cW1, nW1, nW2,
                                                   Wt3, e1pt, e2t, c1t, n1t, n2t);
    conv_h<<<(N_PAD * 512 / 8) / 256, 256, 0, stream>>>(h, hb);

    precompute_X<<<dim3(N_PAD / 32, 3), 256, 0, stream>>>(hb, Wt3, Xb);

    edge_kernel<<<E_EDGES / EB, 256, 0, stream>>>(
        Xb, pos, eidx, eattr, e1pt, eb1, e2t, eb2, c1t, cb1, cW2,
        agg_node, agg_coord);

    node_kernel<<<N_PAD / 32, 256, 0, stream>>>(
        Xb, agg_node, agg_coord, pos, n1t, nb1, n2t, nb2, out);
}

// Round 4
// 372.168 us; speedup vs baseline: 5.3467x; 1.0675x over previous
//
#include <hip/hip_runtime.h>
#include <hip/hip_bf16.h>

#define N_NODES 10000
#define N_PAD   10016
#define E_EDGES 160000
#define EB 32
#define HID 256

typedef __attribute__((ext_vector_type(4))) float f32x4;
typedef __attribute__((ext_vector_type(8))) short bf16x8;
typedef __attribute__((ext_vector_type(8))) unsigned short u16x8;
typedef unsigned short u16;

__device__ __forceinline__ float silu_f(float x) { return x / (1.0f + __expf(-x)); }

__device__ __forceinline__ u16 f2bf(float f) {           // round-to-nearest-even
    unsigned x = __float_as_uint(f);
    unsigned r = x + 0x7FFFu + ((x >> 16) & 1u);
    return (u16)(r >> 16);
}
__device__ __forceinline__ float bf2f(u16 u) {
    return __uint_as_float(((unsigned)u) << 16);
}
__device__ __forceinline__ f32x4 mfma16(bf16x8 a, bf16x8 b, f32x4 c) {
    return __builtin_amdgcn_mfma_f32_16x16x32_bf16(a, b, c, 0, 0, 0);
}
// swizzled byte offset into a [rows][256] u16 activation tile (stride 512B)
__device__ __forceinline__ int actb(int row, int elem) {
    return (row * 512 + elem * 2) ^ ((row & 7) << 4);
}

// ---------------------------------------------------------------------------
// prep: weight transposes -> bf16 [n][k] layouts
// ---------------------------------------------------------------------------
__global__ __launch_bounds__(256) void prep_weights(
    const float* __restrict__ eW1, const float* __restrict__ eW2,
    const float* __restrict__ cW1, const float* __restrict__ nW1,
    const float* __restrict__ nW2,
    u16* __restrict__ Wt3, u16* __restrict__ e1pt, u16* __restrict__ e2t,
    u16* __restrict__ c1t, u16* __restrict__ n1t, u16* __restrict__ n2t)
{
    const int y = blockIdx.y;
    const float* src; u16* dst; int Ks, Kd;
    switch (y) {
        case 0: src = eW1;                dst = Wt3;                Ks = 512; Kd = 512; break;
        case 1: src = eW1 + 512 * 256;    dst = Wt3 + 256 * 512;    Ks = 512; Kd = 512; break;
        case 2: src = nW1;                dst = Wt3 + 2 * 256 * 512; Ks = 512; Kd = 512; break;
        case 3: src = eW1 + 1024 * 256;   dst = e1pt;               Ks = 52;  Kd = 64;  break; // attr rows + radial row (1075)
        case 4: src = eW2;                dst = e2t;                Ks = 256; Kd = 256; break;
        case 5: src = cW1;                dst = c1t;                Ks = 256; Kd = 256; break;
        case 6: src = nW1 + 512 * 256;    dst = n1t;                Ks = 256; Kd = 256; break;
        default: src = nW2;               dst = n2t;                Ks = 256; Kd = 256; break;
    }
    int idx = blockIdx.x * 256 + threadIdx.x;
    if (idx < 256 * Kd) {
        int n = idx / Kd, k = idx - n * Kd;
        dst[idx] = (k < Ks) ? f2bf(src[(size_t)k * 256 + n]) : (u16)0;
    }
}

// h (f32) -> h_bf (bf16), zero-padded rows to N_PAD
__global__ __launch_bounds__(256) void conv_h(const float* __restrict__ h, u16* __restrict__ hb)
{
    size_t base = ((size_t)blockIdx.x * 256 + threadIdx.x) * 8;
    int row = (int)(base >> 9);
    u16x8 o;
    if (row < N_NODES) {
        const float4 f0 = *(const float4*)&h[base];
        const float4 f1 = *(const float4*)&h[base + 4];
        o[0] = f2bf(f0.x); o[1] = f2bf(f0.y); o[2] = f2bf(f0.z); o[3] = f2bf(f0.w);
        o[4] = f2bf(f1.x); o[5] = f2bf(f1.y); o[6] = f2bf(f1.z); o[7] = f2bf(f1.w);
    } else {
        o = (u16x8)0;
    }
    *(u16x8*)&hb[base] = o;
}

// ---------------------------------------------------------------------------
// counting sort of edges by destination row: hist -> scan -> scatter
// ---------------------------------------------------------------------------
__global__ __launch_bounds__(256) void hist_kernel(const int* __restrict__ row,
                                                   int* __restrict__ hist)
{
    int e = blockIdx.x * 256 + threadIdx.x;
    if (e < E_EDGES) atomicAdd(&hist[row[e]], 1);
}

#define SCAN_PER 40   // 256*40 >= N_PAD
__global__ __launch_bounds__(256) void scan_kernel(const int* __restrict__ hist,
                                                   int* __restrict__ rowptr)
{
    __shared__ int a[256];
    const int t = threadIdx.x;
    const int base = t * SCAN_PER;
    int s = 0;
    for (int i = 0; i < SCAN_PER; ++i) {
        int b = base + i;
        if (b < N_PAD) s += hist[b];
    }
    a[t] = s;
    __syncthreads();
    for (int off = 1; off < 256; off <<= 1) {
        int v = (t >= off) ? a[t - off] : 0;
        __syncthreads();
        a[t] += v;
        __syncthreads();
    }
    int run = a[t] - s;      // exclusive base for this thread's span
    for (int i = 0; i < SCAN_PER; ++i) {
        int b = base + i;
        if (b < N_PAD) { rowptr[b] = run; run += hist[b]; }
    }
    if (t == 255) rowptr[N_PAD] = a[255];
}

__global__ __launch_bounds__(256) void scatter_kernel(const int* __restrict__ row,
                                                      const int* __restrict__ rowptr,
                                                      int* __restrict__ cnt,
                                                      int* __restrict__ eorder)
{
    int e = blockIdx.x * 256 + threadIdx.x;
    if (e < E_EDGES) {
        int r = row[e];
        int p = rowptr[r] + atomicAdd(&cnt[r], 1);
        eorder[p] = e;
    }
}

// ---------------------------------------------------------------------------
// Xb[n][0:256]=h@eW1[:512], [256:512]=h@eW1[512:1024], [512:768]=h@nW1[:512] (bf16)
// ---------------------------------------------------------------------------
__global__ __launch_bounds__(256) void precompute_X(
    const u16* __restrict__ hb, const u16* __restrict__ Wt3, u16* __restrict__ Xb)
{
    const int n0b = blockIdx.x * 32;
    const int which = blockIdx.y;
    const int j = threadIdx.x, wv = j >> 6, lane = j & 63;
    const int ml = lane & 15, g = lane >> 4;
    const int n0 = wv * 64;
    const u16* W = Wt3 + (size_t)which * 256 * 512;

    f32x4 acc[2][4];
    const f32x4 z = {0.f, 0.f, 0.f, 0.f};
#pragma unroll
    for (int mt = 0; mt < 2; ++mt)
#pragma unroll
        for (int nt = 0; nt < 4; ++nt) acc[mt][nt] = z;

    for (int kc = 0; kc < 16; ++kc) {
        bf16x8 a0 = *(const bf16x8*)&hb[(size_t)(n0b + ml) * 512 + kc * 32 + g * 8];
        bf16x8 a1 = *(const bf16x8*)&hb[(size_t)(n0b + 16 + ml) * 512 + kc * 32 + g * 8];
#pragma unroll
        for (int nt = 0; nt < 4; ++nt) {
            bf16x8 b = *(const bf16x8*)&W[(size_t)(n0 + nt * 16 + ml) * 512 + kc * 32 + g * 8];
            acc[0][nt] = mfma16(a0, b, acc[0][nt]);
            acc[1][nt] = mfma16(a1, b, acc[1][nt]);
        }
    }
#pragma unroll
    for (int mt = 0; mt < 2; ++mt)
#pragma unroll
        for (int nt = 0; nt < 4; ++nt) {
            int col = n0 + nt * 16 + ml;
#pragma unroll
            for (int i = 0; i < 4; ++i) {
                int row = n0b + mt * 16 + g * 4 + i;
                Xb[(size_t)row * 768 + which * 256 + col] = f2bf(acc[mt][nt][i]);
            }
        }
}

// ---------------------------------------------------------------------------
// edge kernel: 32 SORTED edges/block, 4 waves. Run-length reduced aggregation:
// one atomic per distinct destination row per column (~3/block vs 32/block).
// ---------------------------------------------------------------------------
__global__ __launch_bounds__(256) void edge_kernel(
    const u16* __restrict__ Xb, const float* __restrict__ pos,
    const int* __restrict__ eidx, const float* __restrict__ eattr,
    const int* __restrict__ eorder,
    const u16* __restrict__ e1pt, const float* __restrict__ eb1,
    const u16* __restrict__ e2t, const float* __restrict__ eb2,
    const u16* __restrict__ c1t, const float* __restrict__ cb1,
    const float* __restrict__ cW2,
    float* __restrict__ agg_node, float* __restrict__ agg_coord)
{
    __shared__ u16 attr[EB * 64];    // swizzled, stride 128B
    __shared__ u16 bufA[EB * 256];   // xsum (Xr+Xc), later act2 (swizzled)
    __shared__ u16 bufB[EB * 256];   // act1 (swizzled)
    __shared__ int es[EB];
    __shared__ int ri[EB], ci[EB];
    __shared__ float dif[EB][3];
    __shared__ float rad[EB];
    __shared__ float red[4 * EB];
    __shared__ float uu[EB];

    const int e0 = blockIdx.x * EB;
    const int j = threadIdx.x, wv = j >> 6, lane = j & 63;
    const int ml = lane & 15, g = lane >> 4;
    const int n0 = wv * 64;
    const f32x4 z = {0.f, 0.f, 0.f, 0.f};

    if (j < EB) {
        int e = eorder[e0 + j];
        es[j] = e;
        int r = eidx[e], c = eidx[E_EDGES + e];
        ri[j] = r; ci[j] = c;
        float dx = pos[r * 3 + 0] - pos[c * 3 + 0];
        float dy = pos[r * 3 + 1] - pos[c * 3 + 1];
        float dz = pos[r * 3 + 2] - pos[c * 3 + 2];
        dif[j][0] = dx; dif[j][1] = dy; dif[j][2] = dz;
        rad[j] = sqrtf(dx * dx + dy * dy + dz * dz) + 1e-8f;
    }
    __syncthreads();

    // ---- cooperative wide gather: bufA[e][:] = Xr[ri[e]] + Xc[ci[e]] (bf16)
#pragma unroll
    for (int t = 0; t < 4; ++t) {
        int li = t * 256 + j;           // (edge, 16B-chunk)
        int e = li >> 5, c = li & 31;
        const u16x8 xr = *(const u16x8*)&Xb[(size_t)ri[e] * 768 + c * 8];
        const u16x8 xc = *(const u16x8*)&Xb[(size_t)ci[e] * 768 + 256 + c * 8];
        u16x8 o;
#pragma unroll
        for (int k = 0; k < 8; ++k) o[k] = f2bf(bf2f(xr[k]) + bf2f(xc[k]));
        *(u16x8*)((char*)bufA + ((e * 512 + c * 16) ^ ((e & 7) << 4))) = o;
    }
    // ---- stage edge_attr (+radial in col 51), rows via sorted edge ids
    for (int li = j; li < EB * 64; li += 256) {
        int row = li >> 6, k = li & 63;
        float v = (k < 51) ? eattr[(size_t)es[row] * 51 + k] : (k == 51 ? rad[row] : 0.f);
        int byte = (row * 128 + k * 2) ^ ((row & 7) << 4);
        attr[byte >> 1] = f2bf(v);
    }
    __syncthreads();

    f32x4 acc[2][4];

    // ---- stage 1: attr/radial MFMA (K=64) + bias + xsum, silu -> bufB
#pragma unroll
    for (int mt = 0; mt < 2; ++mt)
#pragma unroll
        for (int nt = 0; nt < 4; ++nt) acc[mt][nt] = z;
#pragma unroll
    for (int kc = 0; kc < 2; ++kc) {
        bf16x8 a0 = *(const bf16x8*)((const char*)attr + ((ml * 128 + (kc * 32 + g * 8) * 2) ^ ((ml & 7) << 4)));
        bf16x8 a1 = *(const bf16x8*)((const char*)attr + (((16 + ml) * 128 + (kc * 32 + g * 8) * 2) ^ ((ml & 7) << 4)));
#pragma unroll
        for (int nt = 0; nt < 4; ++nt) {
            bf16x8 b = *(const bf16x8*)&e1pt[(size_t)(n0 + nt * 16 + ml) * 64 + kc * 32 + g * 8];
            acc[0][nt] = mfma16(a0, b, acc[0][nt]);
            acc[1][nt] = mfma16(a1, b, acc[1][nt]);
        }
    }
#pragma unroll
    for (int mt = 0; mt < 2; ++mt)
#pragma unroll
        for (int nt = 0; nt < 4; ++nt) {
            int col = n0 + nt * 16 + ml;
            float b1 = eb1[col];
#pragma unroll
            for (int i = 0; i < 4; ++i) {
                int m = mt * 16 + g * 4 + i;
                float v = acc[mt][nt][i] + b1 + bf2f(bufA[actb(m, col) >> 1]);
                bufB[actb(m, col) >> 1] = f2bf(silu_f(v));
            }
        }
    __syncthreads();

    // ---- stage 2: e = silu(bufB @ eW2 + eb2) -> bufA (no atomics here)
#pragma unroll
    for (int mt = 0; mt < 2; ++mt)
#pragma unroll
        for (int nt = 0; nt < 4; ++nt) acc[mt][nt] = z;
    for (int kc = 0; kc < 8; ++kc) {
        bf16x8 a0 = *(const bf16x8*)((const char*)bufB + actb(ml, kc * 32 + g * 8));
        bf16x8 a1 = *(const bf16x8*)((const char*)bufB + actb(16 + ml, kc * 32 + g * 8));
#pragma unroll
        for (int nt = 0; nt < 4; ++nt) {
            bf16x8 b = *(const bf16x8*)&e2t[(size_t)(n0 + nt * 16 + ml) * 256 + kc * 32 + g * 8];
            acc[0][nt] = mfma16(a0, b, acc[0][nt]);
            acc[1][nt] = mfma16(a1, b, acc[1][nt]);
        }
    }
#pragma unroll
    for (int mt = 0; mt < 2; ++mt)
#pragma unroll
        for (int nt = 0; nt < 4; ++nt) {
            int col = n0 + nt * 16 + ml;
            float b2 = eb2[col];
#pragma unroll
            for (int i = 0; i < 4; ++i) {
                int m = mt * 16 + g * 4 + i;
                bufA[actb(m, col) >> 1] = f2bf(silu_f(acc[mt][nt][i] + b2));
            }
        }
    __syncthreads();

    // ---- run-length reduced agg_node: thread j owns column j; rows sorted,
    // branch is wave-uniform (ri in LDS), one atomic per distinct row.
    {
        int cur = ri[0];
        float s = bf2f(bufA[actb(0, j) >> 1]);
        for (int m = 1; m < EB; ++m) {
            int r = ri[m];
            float v = bf2f(bufA[actb(m, j) >> 1]);
            if (r != cur) {
                atomicAdd(&agg_node[(size_t)cur * 256 + j], s);
                s = 0.f; cur = r;
            }
            s += v;
        }
        atomicAdd(&agg_node[(size_t)cur * 256 + j], s);
    }

    // ---- stage 3: u = clip((silu(bufA @ cW1 + cb1)) . cW2)
#pragma unroll
    for (int mt = 0; mt < 2; ++mt)
#pragma unroll
        for (int nt = 0; nt < 4; ++nt) acc[mt][nt] = z;
    for (int kc = 0; kc < 8; ++kc) {
        bf16x8 a0 = *(const bf16x8*)((const char*)bufA + actb(ml, kc * 32 + g * 8));
        bf16x8 a1 = *(const bf16x8*)((const char*)bufA + actb(16 + ml, kc * 32 + g * 8));
#pragma unroll
        for (int nt = 0; nt < 4; ++nt) {
            bf16x8 b = *(const bf16x8*)&c1t[(size_t)(n0 + nt * 16 + ml) * 256 + kc * 32 + g * 8];
            acc[0][nt] = mfma16(a0, b, acc[0][nt]);
            acc[1][nt] = mfma16(a1, b, acc[1][nt]);
        }
    }
    float p[2][4] = {{0.f, 0.f, 0.f, 0.f}, {0.f, 0.f, 0.f, 0.f}};
#pragma unroll
    for (int mt = 0; mt < 2; ++mt)
#pragma unroll
        for (int nt = 0; nt < 4; ++nt) {
            int col = n0 + nt * 16 + ml;
            float b3 = cb1[col];
            float w2 = cW2[col];
#pragma unroll
            for (int i = 0; i < 4; ++i)
                p[mt][i] += silu_f(acc[mt][nt][i] + b3) * w2;
        }
#pragma unroll
    for (int mt = 0; mt < 2; ++mt)
#pragma unroll
        for (int i = 0; i < 4; ++i) {
            float v = p[mt][i];
            v += __shfl_xor(v, 1);
            v += __shfl_xor(v, 2);
            v += __shfl_xor(v, 4);
            v += __shfl_xor(v, 8);
            p[mt][i] = v;
        }
    if (ml == 0) {
#pragma unroll
        for (int mt = 0; mt < 2; ++mt)
#pragma unroll
            for (int i = 0; i < 4; ++i)
                red[wv * EB + mt * 16 + g * 4 + i] = p[mt][i];
    }
    __syncthreads();
    if (j < EB) {
        float u = red[j] + red[EB + j] + red[2 * EB + j] + red[3 * EB + j];
        uu[j] = fminf(fmaxf(u, -1.f), 1.f);
    }
    __syncthreads();
    // run-length reduced agg_coord: 3 threads, one atomic per distinct row
    if (j < 3) {
        int cur = ri[0];
        float s = uu[0] * dif[0][j];
        for (int m = 1; m < EB; ++m) {
            int r = ri[m];
            float v = uu[m] * dif[m][j];
            if (r != cur) {
                atomicAdd(&agg_coord[(size_t)cur * 3 + j], s);
                s = 0.f; cur = r;
            }
            s += v;
        }
        atomicAdd(&agg_coord[(size_t)cur * 3 + j], s);
    }
}

// ---------------------------------------------------------------------------
// node kernel: h_new = silu([h,agg] @ nW1 + nb1) @ nW2 + nb2 ; pos update
// ---------------------------------------------------------------------------
__global__ __launch_bounds__(256) void node_kernel(
    const u16* __restrict__ Xb, const float* __restrict__ agg_node,
    const float* __restrict__ agg_coord, const float* __restrict__ pos,
    const u16* __restrict__ n1t, const float* __restrict__ nb1,
    const u16* __restrict__ n2t, const float* __restrict__ nb2,
    float* __restrict__ out)
{
    __shared__ u16 act1[32 * 256];
    __shared__ u16 act2[32 * 256];
    const int n0b = blockIdx.x * 32;
    const int j = threadIdx.x, wv = j >> 6, lane = j & 63;
    const int ml = lane & 15, g = lane >> 4;
    const int n0 = wv * 64;
    const f32x4 z = {0.f, 0.f, 0.f, 0.f};

    for (int li = j; li < 32 * 256; li += 256) {
        int r = li >> 8, c = li & 255;
        act1[actb(r, c) >> 1] = f2bf(agg_node[(size_t)(n0b + r) * 256 + c]);
    }
    __syncthreads();

    f32x4 acc[2][4];
#pragma unroll
    for (int mt = 0; mt < 2; ++mt)
#pragma unroll
        for (int nt = 0; nt < 4; ++nt) acc[mt][nt] = z;
    for (int kc = 0; kc < 8; ++kc) {
        bf16x8 a0 = *(const bf16x8*)((const char*)act1 + actb(ml, kc * 32 + g * 8));
        bf16x8 a1 = *(const bf16x8*)((const char*)act1 + actb(16 + ml, kc * 32 + g * 8));
#pragma unroll
        for (int nt = 0; nt < 4; ++nt) {
            bf16x8 b = *(const bf16x8*)&n1t[(size_t)(n0 + nt * 16 + ml) * 256 + kc * 32 + g * 8];
            acc[0][nt] = mfma16(a0, b, acc[0][nt]);
            acc[1][nt] = mfma16(a1, b, acc[1][nt]);
        }
    }
#pragma unroll
    for (int mt = 0; mt < 2; ++mt)
#pragma unroll
        for (int nt = 0; nt < 4; ++nt) {
            int col = n0 + nt * 16 + ml;
            float b1 = nb1[col];
#pragma unroll
            for (int i = 0; i < 4; ++i) {
                int m = mt * 16 + g * 4 + i;
                float v = acc[mt][nt][i] + b1 + bf2f(Xb[(size_t)(n0b + m) * 768 + 512 + col]);
                act2[actb(m, col) >> 1] = f2bf(silu_f(v));
            }
        }
    __syncthreads();
#pragma unroll
    for (int mt = 0; mt < 2; ++mt)
#pragma unroll
        for (int nt = 0; nt < 4; ++nt) acc[mt][nt] = z;
    for (int kc = 0; kc < 8; ++kc) {
        bf16x8 a0 = *(const bf16x8*)((const char*)act2 + actb(ml, kc * 32 + g * 8));
        bf16x8 a1 = *(const bf16x8*)((const char*)act2 + actb(16 + ml, kc * 32 + g * 8));
#pragma unroll
        for (int nt = 0; nt < 4; ++nt) {
            bf16x8 b = *(const bf16x8*)&n2t[(size_t)(n0 + nt * 16 + ml) * 256 + kc * 32 + g * 8];
            acc[0][nt] = mfma16(a0, b, acc[0][nt]);
            acc[1][nt] = mfma16(a1, b, acc[1][nt]);
        }
    }
#pragma unroll
    for (int mt = 0; mt < 2; ++mt)
#pragma unroll
        for (int nt = 0; nt < 4; ++nt) {
            int col = n0 + nt * 16 + ml;
            float b2 = nb2[col];
#pragma unroll
            for (int i = 0; i < 4; ++i) {
                int row = n0b + mt * 16 + g * 4 + i;
                if (row < N_NODES)
                    out[(size_t)row * 256 + col] = acc[mt][nt][i] + b2;
            }
        }
    if (j < 96) {
        int idx = n0b * 3 + j;
        if (idx < N_NODES * 3)
            out[(size_t)N_NODES * 256 + idx] = pos[idx] + agg_coord[idx];
    }
}

// ---------------------------------------------------------------------------
extern "C" void kernel_launch(void* const* d_in, const int* in_sizes, int n_in,
                              void* d_out, int out_size, void* d_ws, size_t ws_size,
                              hipStream_t stream)
{
    (void)in_sizes; (void)n_in; (void)out_size; (void)ws_size;
    const float* h     = (const float*)d_in[0];
    const int*   eidx  = (const int*)d_in[1];
    const float* eattr = (const float*)d_in[2];
    const float* pos   = (const float*)d_in[3];
    const float* eW1   = (const float*)d_in[4];
    const float* eb1   = (const float*)d_in[5];
    const float* eW2   = (const float*)d_in[6];
    const float* eb2   = (const float*)d_in[7];
    const float* cW1   = (const float*)d_in[8];
    const float* cb1   = (const float*)d_in[9];
    const float* cW2   = (const float*)d_in[10];
    const float* nW1   = (const float*)d_in[11];
    const float* nb1   = (const float*)d_in[12];
    const float* nW2   = (const float*)d_in[13];
    const float* nb2   = (const float*)d_in[14];
    float* out = (float*)d_out;

    u16* Xb   = (u16*)d_ws;                                  // N_PAD*768 bf16
    u16* hb   = Xb + (size_t)N_PAD * 768;                    // N_PAD*512
    u16* Wt3  = hb + (size_t)N_PAD * 512;                    // 3*256*512
    u16* e1pt = Wt3 + 3 * 256 * 512;                         // 256*64
    u16* e2t  = e1pt + 256 * 64;                             // 256*256
    u16* c1t  = e2t + 256 * 256;
    u16* n1t  = c1t + 256 * 256;
    u16* n2t  = n1t + 256 * 256;
    float* agg_node  = (float*)(n2t + 256 * 256);            // N_PAD*256 f32
    float* agg_coord = agg_node + (size_t)N_PAD * 256;       // N_PAD*3  f32
    int* hist   = (int*)(agg_coord + (size_t)N_PAD * 3);     // N_PAD
    int* cnt    = hist + N_PAD;                              // N_PAD
    int* rowptr = cnt + N_PAD;                               // N_PAD+1
    int* eorder = rowptr + N_PAD + 1;                        // E

    hipMemsetAsync(agg_node, 0, (size_t)N_PAD * 259 * sizeof(float), stream);
    hipMemsetAsync(hist, 0, (size_t)2 * N_PAD * sizeof(int), stream);

    prep_weights<<<dim3(512, 8), 256, 0, stream>>>(eW1, eW2, cW1, nW1, nW2,
                                                   Wt3, e1pt, e2t, c1t, n1t, n2t);
    conv_h<<<(N_PAD * 512 / 8) / 256, 256, 0, stream>>>(h, hb);

    hist_kernel<<<(E_EDGES + 255) / 256, 256, 0, stream>>>(eidx, hist);
    scan_kernel<<<1, 256, 0, stream>>>(hist, rowptr);
    scatter_kernel<<<(E_EDGES + 255) / 256, 256, 0, stream>>>(eidx, rowptr, cnt, eorder);

    precompute_X<<<dim3(N_PAD / 32, 3), 256, 0, stream>>>(hb, Wt3, Xb);

    edge_kernel<<<E_EDGES / EB, 256, 0, stream>>>(
        Xb, pos, eidx, eattr, eorder, e1pt, eb1, e2t, eb2, c1t, cb1, cW2,
        agg_node, agg_coord);

    node_kernel<<<N_PAD / 32, 256, 0, stream>>>(
        Xb, agg_node, agg_coord, pos, n1t, nb1, n2t, nb2, out);
}